// Round 1
// baseline (3661.599 us; speedup 1.0000x reference)
//
#include <hip/hip_runtime.h>
#include <hip/hip_bf16.h>

// ---------------------------------------------------------------------------
// 2-layer GAT (H=2 heads, C=64 ch/head, concat l1 / mean l2) + BN + ELU.
// Decomposition:
//   K1  gemm128<0>      : h1 = x @ W1                     -> A
//   K2  attdots         : as1/ad1 = rowdot(h1, att)       (wave/node)
//   K3  edge_max        : emax1[dst] = max leakyrelu(e)   (atomicMax, flip-encoded)
//   K4  edge_acc        : acc1[dst] += h1[src]*ex, den1[dst] += ex   -> B
//       memsetAsync A   : A becomes acc2 (zeroed)
//   K5  l1_finalize     : y = acc1/den + b1 (in-place B) + BN column partial sums
//   K6  bn_final        : bnparam = (scale, shift) per column
//   K7  gemm128<1>      : h2 = elu(bn(y)) @ W2  (in-place B, row-local)
//   K8  attdots         : as2/ad2
//   K9  edge_max        : emax2
//   K10 edge_acc        : acc2 += h2[src]*ex -> A, den2
//   K11 final_out       : out = mean_heads(acc2/den2) + b2
// ---------------------------------------------------------------------------

#define NEG_SLOPE 0.2f
#define BN_EPS 1e-5f

__device__ __forceinline__ unsigned int fflip(float f) {
    unsigned int u = __float_as_uint(f);
    return (u & 0x80000000u) ? ~u : (u | 0x80000000u);
}
__device__ __forceinline__ float funflip(unsigned int u) {
    return __uint_as_float((u & 0x80000000u) ? (u ^ 0x80000000u) : ~u);
}

// ---------------- GEMM: [nrows,128] @ [128,128] -> [nrows,128] --------------
// APPLY_ACT: apply per-column BN scale/shift + ELU to X elements while loading.
// Safe to run in-place (Out == X): a block only reads/writes its own 64 rows,
// and all reads complete before the epilogue stores.
template <int APPLY_ACT>
__global__ __launch_bounds__(256) void gemm128_k(
    const float* __restrict__ X, const float* __restrict__ W,
    float* __restrict__ Out, int nrows, const float* __restrict__ bnparam) {
    __shared__ float Wt[32][128];
    __shared__ float Xt[64][33];
    int row0 = blockIdx.x * 64;
    int tx = threadIdx.x & 31;   // cols tx + 32j
    int ty = threadIdx.x >> 5;   // rows ty + 8i
    float acc[8][4] = {};
    for (int kt = 0; kt < 128; kt += 32) {
        for (int i = threadIdx.x; i < 32 * 128; i += 256)
            Wt[i >> 7][i & 127] = W[(kt + (i >> 7)) * 128 + (i & 127)];
        for (int i = threadIdx.x; i < 64 * 32; i += 256) {
            int r = i >> 5, k = i & 31;
            int row = row0 + r;
            float v = (row < nrows) ? X[(size_t)row * 128 + kt + k] : 0.0f;
            if (APPLY_ACT) {
                float sc = bnparam[kt + k], sh = bnparam[128 + kt + k];
                v = sc * v + sh;
                v = v > 0.0f ? v : (expf(v) - 1.0f);
            }
            Xt[r][k] = v;
        }
        __syncthreads();
        for (int k = 0; k < 32; ++k) {
            float wv[4];
#pragma unroll
            for (int j = 0; j < 4; ++j) wv[j] = Wt[k][tx + 32 * j];
#pragma unroll
            for (int i = 0; i < 8; ++i) {
                float xv = Xt[ty + 8 * i][k];
#pragma unroll
                for (int j = 0; j < 4; ++j) acc[i][j] += xv * wv[j];
            }
        }
        __syncthreads();
    }
    for (int i = 0; i < 8; ++i) {
        int row = row0 + ty + 8 * i;
        if (row < nrows) {
#pragma unroll
            for (int j = 0; j < 4; ++j)
                Out[(size_t)row * 128 + tx + 32 * j] = acc[i][j];
        }
    }
}

// -------- attention dots: as[n,h] = sum_c h[n,h,c]*att_src[h,c] -------------
__global__ __launch_bounds__(256) void attdots_k(
    const float* __restrict__ h, int nrows,
    const float* __restrict__ att_src, const float* __restrict__ att_dst,
    float* __restrict__ as_, float* __restrict__ ad_) {
    int wid = (blockIdx.x * blockDim.x + threadIdx.x) >> 6;
    int lane = threadIdx.x & 63;
    int nw = (gridDim.x * blockDim.x) >> 6;
    for (int n = wid; n < nrows; n += nw) {
        float h0 = h[(size_t)n * 128 + lane];
        float h1 = h[(size_t)n * 128 + 64 + lane];
        float s0 = h0 * att_src[lane];
        float s1 = h1 * att_src[64 + lane];
        float d0 = h0 * att_dst[lane];
        float d1 = h1 * att_dst[64 + lane];
        for (int off = 32; off; off >>= 1) {
            s0 += __shfl_down(s0, off);
            s1 += __shfl_down(s1, off);
            d0 += __shfl_down(d0, off);
            d1 += __shfl_down(d1, off);
        }
        if (lane == 0) {
            as_[n * 2] = s0; as_[n * 2 + 1] = s1;
            ad_[n * 2] = d0; ad_[n * 2 + 1] = d1;
        }
    }
}

// -------- edge pass 1: segment max of leaky_relu(as[src]+ad[dst]) -----------
__global__ __launch_bounds__(256) void edge_max_k(
    const int* __restrict__ src_arr, const int* __restrict__ dst_arr,
    int E_, int Nn, const float* __restrict__ as_, const float* __restrict__ ad_,
    unsigned int* __restrict__ emax) {
    int tid = blockIdx.x * blockDim.x + threadIdx.x;
    int stride = gridDim.x * blockDim.x;
    int total = E_ + Nn;
    for (int e = tid; e < total; e += stride) {
        int s, d;
        if (e < E_) { s = src_arr[e]; d = dst_arr[e]; } else { s = d = e - E_; }
        float e0 = as_[s * 2] + ad_[d * 2];
        float e1 = as_[s * 2 + 1] + ad_[d * 2 + 1];
        e0 = e0 > 0.0f ? e0 : NEG_SLOPE * e0;
        e1 = e1 > 0.0f ? e1 : NEG_SLOPE * e1;
        atomicMax(&emax[d * 2], fflip(e0));
        atomicMax(&emax[d * 2 + 1], fflip(e1));
    }
}

// -------- edge pass 2: acc[dst] += h[src]*ex ; den[dst] += ex ---------------
// one wave per edge; lane l carries float2 (cols 2l,2l+1); head = l>>5
__global__ __launch_bounds__(256) void edge_acc_k(
    const int* __restrict__ src_arr, const int* __restrict__ dst_arr,
    int E_, int Nn, const float* __restrict__ as_, const float* __restrict__ ad_,
    const unsigned int* __restrict__ emax, const float* __restrict__ hsrc,
    float* __restrict__ acc, float* __restrict__ den) {
    int lane = threadIdx.x & 63;
    int wid = (blockIdx.x * blockDim.x + threadIdx.x) >> 6;
    int nw = (gridDim.x * blockDim.x) >> 6;
    int total = E_ + Nn;
    const float2* h2 = (const float2*)hsrc;
    for (int e = wid; e < total; e += nw) {
        int s, d;
        if (e < E_) { s = src_arr[e]; d = dst_arr[e]; } else { s = d = e - E_; }
        float e0 = as_[s * 2] + ad_[d * 2];
        float e1 = as_[s * 2 + 1] + ad_[d * 2 + 1];
        e0 = e0 > 0.0f ? e0 : NEG_SLOPE * e0;
        e1 = e1 > 0.0f ? e1 : NEG_SLOPE * e1;
        float ex0 = expf(e0 - funflip(emax[d * 2]));
        float ex1 = expf(e1 - funflip(emax[d * 2 + 1]));
        if (lane == 0) atomicAdd(&den[d * 2], ex0);
        if (lane == 33) atomicAdd(&den[d * 2 + 1], ex1);
        float2 hv = h2[(size_t)s * 64 + lane];
        float a = (lane < 32) ? ex0 : ex1;
        atomicAdd(&acc[(size_t)d * 128 + 2 * lane], hv.x * a);
        atomicAdd(&acc[(size_t)d * 128 + 2 * lane + 1], hv.y * a);
    }
}

// -------- layer1 finalize: y = acc/den + b1 (in place), BN partial sums -----
__global__ __launch_bounds__(256) void l1_finalize_k(
    float* __restrict__ B, const float* __restrict__ den,
    const float* __restrict__ b1, float* __restrict__ bnsum, int Nn) {
    __shared__ float lsum[128], lsq[128];
    for (int i = threadIdx.x; i < 128; i += blockDim.x) { lsum[i] = 0.0f; lsq[i] = 0.0f; }
    __syncthreads();
    int tid = blockIdx.x * blockDim.x + threadIdx.x;
    int stride = gridDim.x * blockDim.x;   // multiple of 64 -> column fixed per thread
    int total = Nn * 64;
    float2* B2 = (float2*)B;
    int l0 = tid & 63;
    int cpair = l0 * 2;
    const float2 bb = ((const float2*)b1)[l0];
    float s0 = 0, s1 = 0, q0 = 0, q1 = 0;
    for (int i = tid; i < total; i += stride) {
        int n = i >> 6, l = i & 63;
        float dinv = 1.0f / den[n * 2 + (l >> 5)];
        float2 v = B2[i];
        v.x = v.x * dinv + bb.x;
        v.y = v.y * dinv + bb.y;
        B2[i] = v;
        s0 += v.x; s1 += v.y; q0 += v.x * v.x; q1 += v.y * v.y;
    }
    atomicAdd(&lsum[cpair], s0);
    atomicAdd(&lsum[cpair + 1], s1);
    atomicAdd(&lsq[cpair], q0);
    atomicAdd(&lsq[cpair + 1], q1);
    __syncthreads();
    for (int i = threadIdx.x; i < 128; i += blockDim.x) {
        atomicAdd(&bnsum[i], lsum[i]);
        atomicAdd(&bnsum[128 + i], lsq[i]);
    }
}

// -------- BN param finalize -------------------------------------------------
__global__ void bn_final_k(const float* __restrict__ bnsum,
                           const float* __restrict__ gamma,
                           const float* __restrict__ beta,
                           float* __restrict__ bnparam, float invN) {
    int c = threadIdx.x;
    if (c < 128) {
        float mu = bnsum[c] * invN;
        float var = bnsum[128 + c] * invN - mu * mu;
        float sc = gamma[c] * rsqrtf(var + BN_EPS);
        bnparam[c] = sc;
        bnparam[128 + c] = beta[c] - mu * sc;
    }
}

// -------- final: out = 0.5*(acc_h0/den0 + acc_h1/den1) + b2 -----------------
__global__ __launch_bounds__(256) void final_out_k(
    const float* __restrict__ acc, const float* __restrict__ den,
    const float* __restrict__ b2, float* __restrict__ out, int Nn) {
    int tid = blockIdx.x * blockDim.x + threadIdx.x;
    int stride = gridDim.x * blockDim.x;
    int total = Nn * 32;  // float2 per node (64 cols / 2)
    const float2* acc2 = (const float2*)acc;
    float2* out2 = (float2*)out;
    const float2* b22 = (const float2*)b2;
    for (int i = tid; i < total; i += stride) {
        int n = i >> 5, c2 = i & 31;
        float d0 = 1.0f / den[n * 2], d1 = 1.0f / den[n * 2 + 1];
        float2 h0 = acc2[(size_t)n * 64 + c2];
        float2 h1 = acc2[(size_t)n * 64 + 32 + c2];
        float2 bv = b22[c2];
        float2 o;
        o.x = 0.5f * (h0.x * d0 + h1.x * d1) + bv.x;
        o.y = 0.5f * (h0.y * d0 + h1.y * d1) + bv.y;
        out2[i] = o;
    }
}

extern "C" void kernel_launch(void* const* d_in, const int* in_sizes, int n_in,
                              void* d_out, int out_size, void* d_ws, size_t ws_size,
                              hipStream_t stream) {
    const float* x        = (const float*)d_in[0];
    const int*   ei       = (const int*)d_in[1];
    const float* W1       = (const float*)d_in[2];
    const float* att_src1 = (const float*)d_in[3];
    const float* att_dst1 = (const float*)d_in[4];
    const float* b1       = (const float*)d_in[5];
    const float* gamma1   = (const float*)d_in[6];
    const float* beta1    = (const float*)d_in[7];
    const float* W2       = (const float*)d_in[8];
    const float* att_src2 = (const float*)d_in[9];
    const float* att_dst2 = (const float*)d_in[10];
    const float* b2       = (const float*)d_in[11];
    float* out = (float*)d_out;

    const int Nn = in_sizes[0] / 128;
    const int E_ = in_sizes[1] / 2;
    const int* src_arr = ei;
    const int* dst_arr = ei + E_;

    float* ws = (float*)d_ws;
    // workspace layout (floats)
    size_t offB     = 0;                      // Nn*128  acc1 -> y -> h2 (in place)
    size_t offEmax1 = offB + (size_t)Nn * 128;
    size_t offEmax2 = offEmax1 + (size_t)Nn * 2;
    size_t offDen1  = offEmax2 + (size_t)Nn * 2;
    size_t offDen2  = offDen1 + (size_t)Nn * 2;
    size_t offBnsum = offDen2 + (size_t)Nn * 2;
    size_t zeroCnt  = offBnsum + 256;         // [0, zeroCnt) zeroed at start
    size_t offA     = zeroCnt;                // Nn*128  h1 -> acc2
    size_t offAs1   = offA + (size_t)Nn * 128;
    size_t offAd1   = offAs1 + (size_t)Nn * 2;
    size_t offAs2   = offAd1 + (size_t)Nn * 2;
    size_t offAd2   = offAs2 + (size_t)Nn * 2;
    size_t offBnp   = offAd2 + (size_t)Nn * 2;

    float* B       = ws + offB;
    unsigned int* emax1 = (unsigned int*)(ws + offEmax1);
    unsigned int* emax2 = (unsigned int*)(ws + offEmax2);
    float* den1    = ws + offDen1;
    float* den2    = ws + offDen2;
    float* bnsum   = ws + offBnsum;
    float* A       = ws + offA;
    float* as1     = ws + offAs1;
    float* ad1     = ws + offAd1;
    float* as2     = ws + offAs2;
    float* ad2     = ws + offAd2;
    float* bnparam = ws + offBnp;

    // zero: B (acc1) + emax/den/bnsum region in one memset
    hipMemsetAsync(ws, 0, zeroCnt * sizeof(float), stream);

    int gemmBlocks = (Nn + 63) / 64;
    // K1: h1 = x @ W1 -> A
    gemm128_k<0><<<gemmBlocks, 256, 0, stream>>>(x, W1, A, Nn, nullptr);
    // K2: attention dots layer 1
    attdots_k<<<(Nn + 3) / 4, 256, 0, stream>>>(A, Nn, att_src1, att_dst1, as1, ad1);
    // K3: segment max
    edge_max_k<<<2048, 256, 0, stream>>>(src_arr, dst_arr, E_, Nn, as1, ad1, emax1);
    // K4: aggregate
    edge_acc_k<<<8192, 256, 0, stream>>>(src_arr, dst_arr, E_, Nn, as1, ad1, emax1,
                                         A, B, den1);
    // A becomes acc2: zero it
    hipMemsetAsync(A, 0, (size_t)Nn * 128 * sizeof(float), stream);
    // K5: y = acc1/den + b1 (in place in B), BN partial sums
    l1_finalize_k<<<2048, 256, 0, stream>>>(B, den1, b1, bnsum, Nn);
    // K6: BN params
    bn_final_k<<<1, 128, 0, stream>>>(bnsum, gamma1, beta1, bnparam, 1.0f / (float)Nn);
    // K7: h2 = elu(bn(y)) @ W2 (in place in B)
    gemm128_k<1><<<gemmBlocks, 256, 0, stream>>>(B, W2, B, Nn, bnparam);
    // K8: attention dots layer 2
    attdots_k<<<(Nn + 3) / 4, 256, 0, stream>>>(B, Nn, att_src2, att_dst2, as2, ad2);
    // K9: segment max layer 2
    edge_max_k<<<2048, 256, 0, stream>>>(src_arr, dst_arr, E_, Nn, as2, ad2, emax2);
    // K10: aggregate layer 2 -> A
    edge_acc_k<<<8192, 256, 0, stream>>>(src_arr, dst_arr, E_, Nn, as2, ad2, emax2,
                                         B, A, den2);
    // K11: out = mean over heads + b2
    final_out_k<<<2048, 256, 0, stream>>>(A, den2, b2, out, Nn);
    (void)n_in; (void)out_size; (void)ws_size; (void)offBnp;
}

// Round 3
// 953.511 us; speedup vs baseline: 3.8401x; 3.8401x over previous
//
#include <hip/hip_runtime.h>
#include <hip/hip_bf16.h>

// ---------------------------------------------------------------------------
// 2-layer GAT (H=2, C=64) + BN + ELU. Round 2 (resubmit): CSR gather.
//   memset           : cnt + bnsum zero
//   K1 hist          : cnt[dst]++  (int atomics)
//   K2 scan          : rowptr = exclusive_scan(cnt); cursor=rowptr (in cnt)
//   K3 scatter       : csr[atomicAdd(cursor[dst])] = src
//   K4 gemm<0>       : A = x @ W1
//   K5 attdots       : as/ad from A
//   K6 gather<1>     : B[n] = softmax-aggregate + b1 ; BN partial sums
//   K7 bn_final      : bnparam
//   K8 gemm<1>       : B = elu(bn(B)) @ W2   (in place)
//   K9 attdots       : as/ad from B
//   K10 gather<2>    : out[n] = head-mean aggregate + b2
// Self-loops handled inline in gather (not stored in CSR).
// ---------------------------------------------------------------------------

#define NEG_SLOPE 0.2f
#define BN_EPS 1e-5f

// ---------------- GEMM: [nrows,128] @ [128,128] -> [nrows,128] --------------
template <int APPLY_ACT>
__global__ __launch_bounds__(256) void gemm128_k(
    const float* __restrict__ X, const float* __restrict__ W,
    float* __restrict__ Out, int nrows, const float* __restrict__ bnparam) {
    __shared__ float Wt[32][128];
    __shared__ float Xt[64][33];
    int row0 = blockIdx.x * 64;
    int tx = threadIdx.x & 31;
    int ty = threadIdx.x >> 5;
    float acc[8][4] = {};
    for (int kt = 0; kt < 128; kt += 32) {
        for (int i = threadIdx.x; i < 32 * 128; i += 256)
            Wt[i >> 7][i & 127] = W[(kt + (i >> 7)) * 128 + (i & 127)];
        for (int i = threadIdx.x; i < 64 * 32; i += 256) {
            int r = i >> 5, k = i & 31;
            int row = row0 + r;
            float v = (row < nrows) ? X[(size_t)row * 128 + kt + k] : 0.0f;
            if (APPLY_ACT) {
                float sc = bnparam[kt + k], sh = bnparam[128 + kt + k];
                v = sc * v + sh;
                v = v > 0.0f ? v : (expf(v) - 1.0f);
            }
            Xt[r][k] = v;
        }
        __syncthreads();
        for (int k = 0; k < 32; ++k) {
            float wv[4];
#pragma unroll
            for (int j = 0; j < 4; ++j) wv[j] = Wt[k][tx + 32 * j];
#pragma unroll
            for (int i = 0; i < 8; ++i) {
                float xv = Xt[ty + 8 * i][k];
#pragma unroll
                for (int j = 0; j < 4; ++j) acc[i][j] += xv * wv[j];
            }
        }
        __syncthreads();
    }
    for (int i = 0; i < 8; ++i) {
        int row = row0 + ty + 8 * i;
        if (row < nrows) {
#pragma unroll
            for (int j = 0; j < 4; ++j)
                Out[(size_t)row * 128 + tx + 32 * j] = acc[i][j];
        }
    }
}

// -------- attention dots ----------------------------------------------------
__global__ __launch_bounds__(256) void attdots_k(
    const float* __restrict__ h, int nrows,
    const float* __restrict__ att_src, const float* __restrict__ att_dst,
    float* __restrict__ as_, float* __restrict__ ad_) {
    int wid = (blockIdx.x * blockDim.x + threadIdx.x) >> 6;
    int lane = threadIdx.x & 63;
    int nw = (gridDim.x * blockDim.x) >> 6;
    for (int n = wid; n < nrows; n += nw) {
        float h0 = h[(size_t)n * 128 + lane];
        float h1 = h[(size_t)n * 128 + 64 + lane];
        float s0 = h0 * att_src[lane];
        float s1 = h1 * att_src[64 + lane];
        float d0 = h0 * att_dst[lane];
        float d1 = h1 * att_dst[64 + lane];
        for (int off = 32; off; off >>= 1) {
            s0 += __shfl_down(s0, off);
            s1 += __shfl_down(s1, off);
            d0 += __shfl_down(d0, off);
            d1 += __shfl_down(d1, off);
        }
        if (lane == 0) {
            as_[n * 2] = s0; as_[n * 2 + 1] = s1;
            ad_[n * 2] = d0; ad_[n * 2 + 1] = d1;
        }
    }
}

// -------- CSR build ---------------------------------------------------------
__global__ __launch_bounds__(256) void hist_k(const int* __restrict__ dst_arr,
                                              int E_, int* __restrict__ cnt) {
    int tid = blockIdx.x * blockDim.x + threadIdx.x;
    int stride = gridDim.x * blockDim.x;
    for (int e = tid; e < E_; e += stride) atomicAdd(&cnt[dst_arr[e]], 1);
}

// single-block exclusive scan of cnt[0..Nn) (+ total at rowptr[Nn]);
// also copies the exclusive value back into cnt[] as the scatter cursor.
__global__ __launch_bounds__(1024) void scan_k(int* __restrict__ cntcur,
                                               int* __restrict__ rowptr, int Nn) {
    __shared__ int wsum[16];
    __shared__ int s_total;
    __shared__ int s_carry;
    int t = threadIdx.x;
    int lane = t & 63, wave = t >> 6;
    if (t == 0) s_carry = 0;
    __syncthreads();
    int total_elems = Nn + 1;
    for (int base = 0; base < total_elems; base += 1024) {
        int i = base + t;
        int v = (i < Nn) ? cntcur[i] : 0;
        int x = v;
        for (int off = 1; off < 64; off <<= 1) {
            int r = __shfl_up(x, off);
            if (lane >= off) x += r;
        }
        if (lane == 63) wsum[wave] = x;
        __syncthreads();
        if (t == 0) {
            int run = 0;
            for (int w = 0; w < 16; ++w) { int tmp = wsum[w]; wsum[w] = run; run += tmp; }
            s_total = run;
        }
        __syncthreads();
        int excl = x - v + wsum[wave] + s_carry;
        if (i < total_elems) {
            rowptr[i] = excl;
            if (i < Nn) cntcur[i] = excl;
        }
        __syncthreads();
        if (t == 0) s_carry += s_total;
        __syncthreads();
    }
}

__global__ __launch_bounds__(256) void scatter_k(const int* __restrict__ src_arr,
                                                 const int* __restrict__ dst_arr,
                                                 int E_, int* __restrict__ cursor,
                                                 int* __restrict__ csr) {
    int tid = blockIdx.x * blockDim.x + threadIdx.x;
    int stride = gridDim.x * blockDim.x;
    for (int e = tid; e < E_; e += stride) {
        int d = dst_arr[e];
        int pos = atomicAdd(&cursor[d], 1);
        csr[pos] = src_arr[e];
    }
}

// -------- gather: one wave per dst node, online softmax in registers --------
// LAYER 1: outp = y[n,128] = agg + b1 ; accumulate BN col sums into bnsum
// LAYER 2: outp = out[n,64] = 0.5*(head0+head1) + b2
template <int LAYER>
__global__ __launch_bounds__(256) void gather_k(
    const int* __restrict__ csr, const int* __restrict__ rowptr,
    const float* __restrict__ as_, const float* __restrict__ ad_,
    const float* __restrict__ hfeat, float* __restrict__ outp,
    const float* __restrict__ bias, float* __restrict__ bnsum, int Nn) {
    int lane = threadIdx.x & 63;
    int wid = (blockIdx.x * blockDim.x + threadIdx.x) >> 6;
    int nw = (gridDim.x * blockDim.x) >> 6;
    const float2* h2 = (const float2*)hfeat;
    const float2* as2 = (const float2*)as_;
    const float2* ad2 = (const float2*)ad_;
    int head = lane >> 5;
    float s0 = 0, s1 = 0, q0 = 0, q1 = 0;  // BN stats (LAYER 1)
    for (int n = wid; n < Nn; n += nw) {
        int beg = rowptr[n], end = rowptr[n + 1];
        int deg = end - beg;
        float2 adn = ad2[n];
        float2 asn = as2[n];
        float es0 = asn.x + adn.x; es0 = es0 > 0.f ? es0 : NEG_SLOPE * es0;
        float es1 = asn.y + adn.y; es1 = es1 > 0.f ? es1 : NEG_SLOPE * es1;
        float m0 = es0, m1 = es1;
        int s_st = 0; float e0_st = 0.f, e1_st = 0.f;
        // phase A: per-head max over incoming edges (lanes parallel), stash 1st chunk
        for (int j = lane; j < deg; j += 64) {
            int s = csr[beg + j];
            float2 a = as2[s];
            float t0 = a.x + adn.x; t0 = t0 > 0.f ? t0 : NEG_SLOPE * t0;
            float t1 = a.y + adn.y; t1 = t1 > 0.f ? t1 : NEG_SLOPE * t1;
            if (j < 64) { s_st = s; e0_st = t0; e1_st = t1; }
            m0 = fmaxf(m0, t0); m1 = fmaxf(m1, t1);
        }
        for (int off = 32; off; off >>= 1) {
            m0 = fmaxf(m0, __shfl_xor(m0, off));
            m1 = fmaxf(m1, __shfl_xor(m1, off));
        }
        float mh = head ? m1 : m0;
        // self-loop contribution
        float ps = expf((head ? es1 : es0) - mh);
        float den = ps;
        float2 hv = h2[(size_t)n * 64 + lane];
        float2 acc; acc.x = ps * hv.x; acc.y = ps * hv.y;
        // phase B: accumulate edges; broadcast stash via shfl
        for (int j0 = 0; j0 < deg; j0 += 64) {
            int cnt = min(64, deg - j0);
            int sc; float ec0, ec1;
            if (j0 == 0) { sc = s_st; ec0 = e0_st; ec1 = e1_st; }
            else {
                sc = 0; ec0 = 0.f; ec1 = 0.f;
                int j = j0 + lane;
                if (j < deg) {
                    int s = csr[beg + j];
                    float2 a = as2[s];
                    ec0 = a.x + adn.x; ec0 = ec0 > 0.f ? ec0 : NEG_SLOPE * ec0;
                    ec1 = a.y + adn.y; ec1 = ec1 > 0.f ? ec1 : NEG_SLOPE * ec1;
                    sc = s;
                }
            }
            for (int jj = 0; jj < cnt; ++jj) {
                int s = __shfl(sc, jj);
                float eA = __shfl(ec0, jj);
                float eB = __shfl(ec1, jj);
                float p = expf((head ? eB : eA) - mh);
                den += p;
                float2 hvv = h2[(size_t)s * 64 + lane];
                acc.x += p * hvv.x;
                acc.y += p * hvv.y;
            }
        }
        float inv = 1.0f / den;
        if (LAYER == 1) {
            float2 bb = ((const float2*)bias)[lane];
            float2 v; v.x = acc.x * inv + bb.x; v.y = acc.y * inv + bb.y;
            ((float2*)outp)[(size_t)n * 64 + lane] = v;
            s0 += v.x; s1 += v.y; q0 += v.x * v.x; q1 += v.y * v.y;
        } else {
            float vx = acc.x * inv, vy = acc.y * inv;
            float vx2 = __shfl(vx, lane + 32);
            float vy2 = __shfl(vy, lane + 32);
            if (lane < 32) {
                float2 bb = ((const float2*)bias)[lane];
                float2 o;
                o.x = 0.5f * (vx + vx2) + bb.x;
                o.y = 0.5f * (vy + vy2) + bb.y;
                ((float2*)outp)[(size_t)n * 32 + lane] = o;
            }
        }
    }
    if (LAYER == 1) {
        __shared__ float lsum[128], lsq[128];
        if (threadIdx.x < 128) { lsum[threadIdx.x] = 0.f; lsq[threadIdx.x] = 0.f; }
        __syncthreads();
        atomicAdd(&lsum[2 * lane], s0);
        atomicAdd(&lsum[2 * lane + 1], s1);
        atomicAdd(&lsq[2 * lane], q0);
        atomicAdd(&lsq[2 * lane + 1], q1);
        __syncthreads();
        if (threadIdx.x < 128) {
            atomicAdd(&bnsum[threadIdx.x], lsum[threadIdx.x]);
            atomicAdd(&bnsum[128 + threadIdx.x], lsq[threadIdx.x]);
        }
    }
}

// -------- BN param finalize -------------------------------------------------
__global__ void bn_final_k(const float* __restrict__ bnsum,
                           const float* __restrict__ gamma,
                           const float* __restrict__ beta,
                           float* __restrict__ bnparam, float invN) {
    int c = threadIdx.x;
    if (c < 128) {
        float mu = bnsum[c] * invN;
        float var = bnsum[128 + c] * invN - mu * mu;
        float sc = gamma[c] * rsqrtf(var + BN_EPS);
        bnparam[c] = sc;
        bnparam[128 + c] = beta[c] - mu * sc;
    }
}

extern "C" void kernel_launch(void* const* d_in, const int* in_sizes, int n_in,
                              void* d_out, int out_size, void* d_ws, size_t ws_size,
                              hipStream_t stream) {
    const float* x        = (const float*)d_in[0];
    const int*   ei       = (const int*)d_in[1];
    const float* W1       = (const float*)d_in[2];
    const float* att_src1 = (const float*)d_in[3];
    const float* att_dst1 = (const float*)d_in[4];
    const float* b1       = (const float*)d_in[5];
    const float* gamma1   = (const float*)d_in[6];
    const float* beta1    = (const float*)d_in[7];
    const float* W2       = (const float*)d_in[8];
    const float* att_src2 = (const float*)d_in[9];
    const float* att_dst2 = (const float*)d_in[10];
    const float* b2       = (const float*)d_in[11];
    float* out = (float*)d_out;

    const int Nn = in_sizes[0] / 128;
    const int E_ = in_sizes[1] / 2;
    const int* src_arr = ei;
    const int* dst_arr = ei + E_;

    float* ws = (float*)d_ws;
    // layout (floats, each region 16B-aligned)
    auto a4 = [](size_t v) { return (v + 3) & ~(size_t)3; };
    size_t off = 0;
    size_t offCnt   = off; off = a4(off + (size_t)Nn);        // cnt/cursor (int)
    size_t offBnsum = off; off = a4(off + 256);               // zeroed with cnt
    size_t zeroCnt  = off;                                    // [0, zeroCnt) zeroed
    size_t offRow   = off; off = a4(off + (size_t)Nn + 1);    // rowptr (int)
    size_t offAs    = off; off = a4(off + (size_t)Nn * 2);
    size_t offAd    = off; off = a4(off + (size_t)Nn * 2);
    size_t offBnp   = off; off = a4(off + 256);
    size_t offCsr   = off; off = a4(off + (size_t)E_);        // csr src (int)
    size_t offB     = off; off = a4(off + (size_t)Nn * 128);  // y / h2
    size_t offA     = off; off = a4(off + (size_t)Nn * 128);  // h1

    int*   cnt     = (int*)(ws + offCnt);
    float* bnsum   = ws + offBnsum;
    int*   rowptr  = (int*)(ws + offRow);
    float* as_     = ws + offAs;
    float* ad_     = ws + offAd;
    float* bnparam = ws + offBnp;
    int*   csr     = (int*)(ws + offCsr);
    float* B       = ws + offB;
    float* A       = ws + offA;

    hipMemsetAsync(ws, 0, zeroCnt * sizeof(float), stream);

    // CSR build (graph shared by both layers)
    hist_k<<<2048, 256, 0, stream>>>(dst_arr, E_, cnt);
    scan_k<<<1, 1024, 0, stream>>>(cnt, rowptr, Nn);
    scatter_k<<<2048, 256, 0, stream>>>(src_arr, dst_arr, E_, cnt, csr);

    int gemmBlocks = (Nn + 63) / 64;
    // layer 1
    gemm128_k<0><<<gemmBlocks, 256, 0, stream>>>(x, W1, A, Nn, nullptr);
    attdots_k<<<(Nn + 3) / 4, 256, 0, stream>>>(A, Nn, att_src1, att_dst1, as_, ad_);
    gather_k<1><<<2048, 256, 0, stream>>>(csr, rowptr, as_, ad_, A, B, b1, bnsum, Nn);
    bn_final_k<<<1, 128, 0, stream>>>(bnsum, gamma1, beta1, bnparam, 1.0f / (float)Nn);
    // layer 2
    gemm128_k<1><<<gemmBlocks, 256, 0, stream>>>(B, W2, B, Nn, bnparam);
    attdots_k<<<(Nn + 3) / 4, 256, 0, stream>>>(B, Nn, att_src2, att_dst2, as_, ad_);
    gather_k<2><<<2048, 256, 0, stream>>>(csr, rowptr, as_, ad_, B, out, b2, nullptr, Nn);

    (void)n_in; (void)out_size; (void)ws_size;
}

// Round 5
// 797.494 us; speedup vs baseline: 4.5914x; 1.1956x over previous
//
#include <hip/hip_runtime.h>
#include <hip/hip_bf16.h>

// ---------------------------------------------------------------------------
// 2-layer GAT (H=2, C=64) + BN + ELU.  Round 4 (resubmit — broker timeout):
//   - h1/h2 feature tables stored as bf16 (halves gather traffic); all
//     accumulation/softmax/BN/y/out stay fp32.
//   - 3-phase parallel scan replaces single-block scan.
// Pipeline:
//   memset; hist; scan_part/scan_psum/scan_final; scatter;
//   gemm<0> x@W1 -> h1(bf16); attdots(h1); gather<1> -> y(fp32)+BN sums;
//   bn_final; gemm<1> elu(bn(y))@W2 -> h2(bf16); attdots(h2);
//   gather<2> -> out(fp32)
// ---------------------------------------------------------------------------

#define NEG_SLOPE 0.2f
#define BN_EPS 1e-5f
#define SCHUNK 4096

__device__ __forceinline__ float bf_lo(unsigned int u) { return __uint_as_float(u << 16); }
__device__ __forceinline__ float bf_hi(unsigned int u) { return __uint_as_float(u & 0xffff0000u); }
__device__ __forceinline__ unsigned short f2bf(float v) {
    unsigned int b = __float_as_uint(v);
    b += 0x7fffu + ((b >> 16) & 1u);
    return (unsigned short)(b >> 16);
}

// ---------------- GEMM: [nrows,128](fp32) @ [128,128](fp32) -> bf16 ---------
template <int APPLY_ACT>
__global__ __launch_bounds__(256) void gemm128_k(
    const float* __restrict__ X, const float* __restrict__ W,
    unsigned short* __restrict__ Out, int nrows, const float* __restrict__ bnparam) {
    __shared__ float Wt[32][128];
    __shared__ float Xt[64][33];
    int row0 = blockIdx.x * 64;
    int tx = threadIdx.x & 31;
    int ty = threadIdx.x >> 5;
    float acc[8][4] = {};
    for (int kt = 0; kt < 128; kt += 32) {
        for (int i = threadIdx.x; i < 32 * 128; i += 256)
            Wt[i >> 7][i & 127] = W[(kt + (i >> 7)) * 128 + (i & 127)];
        for (int i = threadIdx.x; i < 64 * 32; i += 256) {
            int r = i >> 5, k = i & 31;
            int row = row0 + r;
            float v = (row < nrows) ? X[(size_t)row * 128 + kt + k] : 0.0f;
            if (APPLY_ACT) {
                float sc = bnparam[kt + k], sh = bnparam[128 + kt + k];
                v = sc * v + sh;
                v = v > 0.0f ? v : (expf(v) - 1.0f);
            }
            Xt[r][k] = v;
        }
        __syncthreads();
        for (int k = 0; k < 32; ++k) {
            float wv[4];
#pragma unroll
            for (int j = 0; j < 4; ++j) wv[j] = Wt[k][tx + 32 * j];
#pragma unroll
            for (int i = 0; i < 8; ++i) {
                float xv = Xt[ty + 8 * i][k];
#pragma unroll
                for (int j = 0; j < 4; ++j) acc[i][j] += xv * wv[j];
            }
        }
        __syncthreads();
    }
    for (int i = 0; i < 8; ++i) {
        int row = row0 + ty + 8 * i;
        if (row < nrows) {
#pragma unroll
            for (int j = 0; j < 4; ++j)
                Out[(size_t)row * 128 + tx + 32 * j] = f2bf(acc[i][j]);
        }
    }
}

// -------- attention dots (bf16 h) -------------------------------------------
__global__ __launch_bounds__(256) void attdots_k(
    const unsigned short* __restrict__ h, int nrows,
    const float* __restrict__ att_src, const float* __restrict__ att_dst,
    float* __restrict__ as_, float* __restrict__ ad_) {
    int wid = (blockIdx.x * blockDim.x + threadIdx.x) >> 6;
    int lane = threadIdx.x & 63;
    int nw = (gridDim.x * blockDim.x) >> 6;
    for (int n = wid; n < nrows; n += nw) {
        float h0 = __uint_as_float((unsigned int)h[(size_t)n * 128 + lane] << 16);
        float h1 = __uint_as_float((unsigned int)h[(size_t)n * 128 + 64 + lane] << 16);
        float s0 = h0 * att_src[lane];
        float s1 = h1 * att_src[64 + lane];
        float d0 = h0 * att_dst[lane];
        float d1 = h1 * att_dst[64 + lane];
        for (int off = 32; off; off >>= 1) {
            s0 += __shfl_down(s0, off);
            s1 += __shfl_down(s1, off);
            d0 += __shfl_down(d0, off);
            d1 += __shfl_down(d1, off);
        }
        if (lane == 0) {
            as_[n * 2] = s0; as_[n * 2 + 1] = s1;
            ad_[n * 2] = d0; ad_[n * 2 + 1] = d1;
        }
    }
}

// -------- CSR build ---------------------------------------------------------
__global__ __launch_bounds__(256) void hist_k(const int* __restrict__ dst_arr,
                                              int E_, int* __restrict__ cnt) {
    int tid = blockIdx.x * blockDim.x + threadIdx.x;
    int stride = gridDim.x * blockDim.x;
    for (int e = tid; e < E_; e += stride) atomicAdd(&cnt[dst_arr[e]], 1);
}

// phase 1: per-chunk sums
__global__ __launch_bounds__(256) void scan_part_k(const int* __restrict__ cnt,
                                                   int Nn, int* __restrict__ partial) {
    int b = blockIdx.x;
    int beg = b * SCHUNK, end = min(Nn, beg + SCHUNK);
    int s = 0;
    for (int i = beg + threadIdx.x; i < end; i += 256) s += cnt[i];
    for (int off = 32; off; off >>= 1) s += __shfl_down(s, off);
    __shared__ int wsum[4];
    int lane = threadIdx.x & 63, w = threadIdx.x >> 6;
    if (lane == 0) wsum[w] = s;
    __syncthreads();
    if (threadIdx.x == 0) partial[b] = wsum[0] + wsum[1] + wsum[2] + wsum[3];
}

// phase 2: serial scan of NB partials (NB ~ 25), writes rowptr[Nn]=total
__global__ void scan_psum_k(int* __restrict__ partial, int NB,
                            int* __restrict__ rowptr, int Nn) {
    if (threadIdx.x == 0) {
        int run = 0;
        for (int i = 0; i < NB; ++i) { int t = partial[i]; partial[i] = run; run += t; }
        rowptr[Nn] = run;
    }
}

// phase 3: per-chunk exclusive scan + chunk offset; writes rowptr + cursor
__global__ __launch_bounds__(256) void scan_final_k(int* __restrict__ cntcur, int Nn,
                                                    const int* __restrict__ partial,
                                                    int* __restrict__ rowptr) {
    int b = blockIdx.x;
    int t = threadIdx.x;
    int i0 = b * SCHUNK + t * 16;
    int v[16];
    int s = 0;
#pragma unroll
    for (int k = 0; k < 16; ++k) {
        int i = i0 + k;
        int val = (i < Nn) ? cntcur[i] : 0;
        v[k] = s; s += val;
    }
    int lane = t & 63, w = t >> 6;
    int x = s;
    for (int off = 1; off < 64; off <<= 1) {
        int r = __shfl_up(x, off);
        if (lane >= off) x += r;
    }
    __shared__ int wsum[4], woff[4];
    if (lane == 63) wsum[w] = x;
    __syncthreads();
    if (t == 0) { int run = 0; for (int j = 0; j < 4; ++j) { woff[j] = run; run += wsum[j]; } }
    __syncthreads();
    int excl = x - s + woff[w] + partial[b];
#pragma unroll
    for (int k = 0; k < 16; ++k) {
        int i = i0 + k;
        if (i < Nn) { int e = excl + v[k]; rowptr[i] = e; cntcur[i] = e; }
    }
}

__global__ __launch_bounds__(256) void scatter_k(const int* __restrict__ src_arr,
                                                 const int* __restrict__ dst_arr,
                                                 int E_, int* __restrict__ cursor,
                                                 int* __restrict__ csr) {
    int tid = blockIdx.x * blockDim.x + threadIdx.x;
    int stride = gridDim.x * blockDim.x;
    for (int e = tid; e < E_; e += stride) {
        int d = dst_arr[e];
        int pos = atomicAdd(&cursor[d], 1);
        csr[pos] = src_arr[e];
    }
}

// -------- gather: one wave per dst node, online softmax, bf16 h rows --------
// LAYER 1: outp = y[n,128] fp32 = agg + b1 ; BN col sums into bnsum
// LAYER 2: outp = out[n,64] fp32 = 0.5*(head0+head1) + b2
template <int LAYER>
__global__ __launch_bounds__(256) void gather_k(
    const int* __restrict__ csr, const int* __restrict__ rowptr,
    const float* __restrict__ as_, const float* __restrict__ ad_,
    const unsigned short* __restrict__ hfeat, float* __restrict__ outp,
    const float* __restrict__ bias, float* __restrict__ bnsum, int Nn) {
    int lane = threadIdx.x & 63;
    int wid = (blockIdx.x * blockDim.x + threadIdx.x) >> 6;
    int nw = (gridDim.x * blockDim.x) >> 6;
    const unsigned int* h4 = (const unsigned int*)hfeat;  // 2 bf16 per uint
    const float2* as2 = (const float2*)as_;
    const float2* ad2 = (const float2*)ad_;
    int head = lane >> 5;
    float s0 = 0, s1 = 0, q0 = 0, q1 = 0;  // BN stats (LAYER 1)
    for (int n = wid; n < Nn; n += nw) {
        int beg = rowptr[n], end = rowptr[n + 1];
        int deg = end - beg;
        float2 adn = ad2[n];
        float2 asn = as2[n];
        float es0 = asn.x + adn.x; es0 = es0 > 0.f ? es0 : NEG_SLOPE * es0;
        float es1 = asn.y + adn.y; es1 = es1 > 0.f ? es1 : NEG_SLOPE * es1;
        float m0 = es0, m1 = es1;
        int s_st = 0; float e0_st = 0.f, e1_st = 0.f;
        // phase A: per-head max over incoming edges; stash first 64 in regs
        for (int j = lane; j < deg; j += 64) {
            int s = csr[beg + j];
            float2 a = as2[s];
            float t0 = a.x + adn.x; t0 = t0 > 0.f ? t0 : NEG_SLOPE * t0;
            float t1 = a.y + adn.y; t1 = t1 > 0.f ? t1 : NEG_SLOPE * t1;
            if (j < 64) { s_st = s; e0_st = t0; e1_st = t1; }
            m0 = fmaxf(m0, t0); m1 = fmaxf(m1, t1);
        }
        for (int off = 32; off; off >>= 1) {
            m0 = fmaxf(m0, __shfl_xor(m0, off));
            m1 = fmaxf(m1, __shfl_xor(m1, off));
        }
        float mh = head ? m1 : m0;
        // self-loop
        float ps = expf((head ? es1 : es0) - mh);
        float den = ps;
        unsigned int hu = h4[(size_t)n * 64 + lane];
        float2 acc; acc.x = ps * bf_lo(hu); acc.y = ps * bf_hi(hu);
        // phase B: accumulate edges; broadcast via shfl
        for (int j0 = 0; j0 < deg; j0 += 64) {
            int cnt = min(64, deg - j0);
            int sc; float ec0, ec1;
            if (j0 == 0) { sc = s_st; ec0 = e0_st; ec1 = e1_st; }
            else {
                sc = 0; ec0 = 0.f; ec1 = 0.f;
                int j = j0 + lane;
                if (j < deg) {
                    int s = csr[beg + j];
                    float2 a = as2[s];
                    ec0 = a.x + adn.x; ec0 = ec0 > 0.f ? ec0 : NEG_SLOPE * ec0;
                    ec1 = a.y + adn.y; ec1 = ec1 > 0.f ? ec1 : NEG_SLOPE * ec1;
                    sc = s;
                }
            }
            for (int jj = 0; jj < cnt; ++jj) {
                int s = __shfl(sc, jj);
                float eA = __shfl(ec0, jj);
                float eB = __shfl(ec1, jj);
                float p = expf((head ? eB : eA) - mh);
                den += p;
                unsigned int hv = h4[(size_t)s * 64 + lane];
                acc.x += p * bf_lo(hv);
                acc.y += p * bf_hi(hv);
            }
        }
        float inv = 1.0f / den;
        if (LAYER == 1) {
            float2 bb = ((const float2*)bias)[lane];
            float2 v; v.x = acc.x * inv + bb.x; v.y = acc.y * inv + bb.y;
            ((float2*)outp)[(size_t)n * 64 + lane] = v;
            s0 += v.x; s1 += v.y; q0 += v.x * v.x; q1 += v.y * v.y;
        } else {
            float vx = acc.x * inv, vy = acc.y * inv;
            float vx2 = __shfl(vx, lane + 32);
            float vy2 = __shfl(vy, lane + 32);
            if (lane < 32) {
                float2 bb = ((const float2*)bias)[lane];
                float2 o;
                o.x = 0.5f * (vx + vx2) + bb.x;
                o.y = 0.5f * (vy + vy2) + bb.y;
                ((float2*)outp)[(size_t)n * 32 + lane] = o;
            }
        }
    }
    if (LAYER == 1) {
        __shared__ float lsum[128], lsq[128];
        if (threadIdx.x < 128) { lsum[threadIdx.x] = 0.f; lsq[threadIdx.x] = 0.f; }
        __syncthreads();
        atomicAdd(&lsum[2 * lane], s0);
        atomicAdd(&lsum[2 * lane + 1], s1);
        atomicAdd(&lsq[2 * lane], q0);
        atomicAdd(&lsq[2 * lane + 1], q1);
        __syncthreads();
        if (threadIdx.x < 128) {
            atomicAdd(&bnsum[threadIdx.x], lsum[threadIdx.x]);
            atomicAdd(&bnsum[128 + threadIdx.x], lsq[threadIdx.x]);
        }
    }
}

// -------- BN param finalize -------------------------------------------------
__global__ void bn_final_k(const float* __restrict__ bnsum,
                           const float* __restrict__ gamma,
                           const float* __restrict__ beta,
                           float* __restrict__ bnparam, float invN) {
    int c = threadIdx.x;
    if (c < 128) {
        float mu = bnsum[c] * invN;
        float var = bnsum[128 + c] * invN - mu * mu;
        float sc = gamma[c] * rsqrtf(var + BN_EPS);
        bnparam[c] = sc;
        bnparam[128 + c] = beta[c] - mu * sc;
    }
}

extern "C" void kernel_launch(void* const* d_in, const int* in_sizes, int n_in,
                              void* d_out, int out_size, void* d_ws, size_t ws_size,
                              hipStream_t stream) {
    const float* x        = (const float*)d_in[0];
    const int*   ei       = (const int*)d_in[1];
    const float* W1       = (const float*)d_in[2];
    const float* att_src1 = (const float*)d_in[3];
    const float* att_dst1 = (const float*)d_in[4];
    const float* b1       = (const float*)d_in[5];
    const float* gamma1   = (const float*)d_in[6];
    const float* beta1    = (const float*)d_in[7];
    const float* W2       = (const float*)d_in[8];
    const float* att_src2 = (const float*)d_in[9];
    const float* att_dst2 = (const float*)d_in[10];
    const float* b2       = (const float*)d_in[11];
    float* out = (float*)d_out;

    const int Nn = in_sizes[0] / 128;
    const int E_ = in_sizes[1] / 2;
    const int* src_arr = ei;
    const int* dst_arr = ei + E_;

    float* ws = (float*)d_ws;
    auto a4 = [](size_t v) { return (v + 3) & ~(size_t)3; };
    size_t off = 0;
    size_t offCnt   = off; off = a4(off + (size_t)Nn);          // cnt/cursor (int)
    size_t offBnsum = off; off = a4(off + 256);                 // zeroed with cnt
    size_t zeroCnt  = off;                                      // [0,zeroCnt) zeroed
    size_t offRow   = off; off = a4(off + (size_t)Nn + 1);      // rowptr (int)
    size_t offPart  = off; off = a4(off + 256);                 // scan partials (int)
    size_t offAs    = off; off = a4(off + (size_t)Nn * 2);
    size_t offAd    = off; off = a4(off + (size_t)Nn * 2);
    size_t offBnp   = off; off = a4(off + 256);
    size_t offCsr   = off; off = a4(off + (size_t)E_);          // csr src (int)
    size_t offY     = off; off = a4(off + (size_t)Nn * 128);    // y fp32
    size_t offH1    = off; off = a4(off + (size_t)Nn * 64);     // h1 bf16 (ushort)
    size_t offH2    = off; off = a4(off + (size_t)Nn * 64);     // h2 bf16 (ushort)

    int*   cnt     = (int*)(ws + offCnt);
    float* bnsum   = ws + offBnsum;
    int*   rowptr  = (int*)(ws + offRow);
    int*   partial = (int*)(ws + offPart);
    float* as_     = ws + offAs;
    float* ad_     = ws + offAd;
    float* bnparam = ws + offBnp;
    int*   csr     = (int*)(ws + offCsr);
    float* Y       = ws + offY;
    unsigned short* H1 = (unsigned short*)(ws + offH1);
    unsigned short* H2 = (unsigned short*)(ws + offH2);

    hipMemsetAsync(ws, 0, zeroCnt * sizeof(float), stream);

    // CSR build
    int NB = (Nn + SCHUNK - 1) / SCHUNK;
    hist_k<<<2048, 256, 0, stream>>>(dst_arr, E_, cnt);
    scan_part_k<<<NB, 256, 0, stream>>>(cnt, Nn, partial);
    scan_psum_k<<<1, 64, 0, stream>>>(partial, NB, rowptr, Nn);
    scan_final_k<<<NB, 256, 0, stream>>>(cnt, Nn, partial, rowptr);
    scatter_k<<<2048, 256, 0, stream>>>(src_arr, dst_arr, E_, cnt, csr);

    int gemmBlocks = (Nn + 63) / 64;
    // layer 1
    gemm128_k<0><<<gemmBlocks, 256, 0, stream>>>(x, W1, H1, Nn, nullptr);
    attdots_k<<<(Nn + 3) / 4, 256, 0, stream>>>(H1, Nn, att_src1, att_dst1, as_, ad_);
    gather_k<1><<<2048, 256, 0, stream>>>(csr, rowptr, as_, ad_, H1, Y, b1, bnsum, Nn);
    bn_final_k<<<1, 128, 0, stream>>>(bnsum, gamma1, beta1, bnparam, 1.0f / (float)Nn);
    // layer 2
    gemm128_k<1><<<gemmBlocks, 256, 0, stream>>>(Y, W2, H2, Nn, bnparam);
    attdots_k<<<(Nn + 3) / 4, 256, 0, stream>>>(H2, Nn, att_src2, att_dst2, as_, ad_);
    gather_k<2><<<2048, 256, 0, stream>>>(csr, rowptr, as_, ad_, H2, out, b2, nullptr, Nn);

    (void)n_in; (void)out_size; (void)ws_size;
}

// Round 6
// 700.034 us; speedup vs baseline: 5.2306x; 1.1392x over previous
//
#include <hip/hip_runtime.h>
#include <hip/hip_bf16.h>

// ---------------------------------------------------------------------------
// 2-layer GAT (H=2, C=64) + BN + ELU.  Round 6:
//   - single-pass gather: online softmax, LDS-staged {p,s}, ds_read_b64
//     broadcast accumulate (unroll 4) — replaces 2-pass shfl-broadcast.
//   - attdots folded into GEMM epilogue (kernel deleted).
// Pipeline:
//   memset; hist; scan_part/psum/final; scatter;
//   gemm<0> x@W1 -> h1(bf16) + as/ad; gather<1> -> y(fp32)+BN sums;
//   bn_final; gemm<1> elu(bn(y))@W2 -> h2(bf16) + as/ad;
//   gather<2> -> out(fp32)
// ---------------------------------------------------------------------------

#define NEG_SLOPE 0.2f
#define BN_EPS 1e-5f
#define SCHUNK 4096

__device__ __forceinline__ float bf_lo(unsigned int u) { return __uint_as_float(u << 16); }
__device__ __forceinline__ float bf_hi(unsigned int u) { return __uint_as_float(u & 0xffff0000u); }
__device__ __forceinline__ unsigned short f2bf(float v) {
    unsigned int b = __float_as_uint(v);
    b += 0x7fffu + ((b >> 16) & 1u);
    return (unsigned short)(b >> 16);
}

// ------- GEMM: [nrows,128](fp32) @ [128,128](fp32) -> bf16 + att dots -------
// Epilogue also computes as[n,h] = sum_c h[n,h,c]*att_src[h,c] (and ad) from
// the fp32 accumulators: width-32 shfl reduction over the tx lanes.
template <int APPLY_ACT>
__global__ __launch_bounds__(256) void gemm128_k(
    const float* __restrict__ X, const float* __restrict__ W,
    unsigned short* __restrict__ Out, int nrows, const float* __restrict__ bnparam,
    const float* __restrict__ att_src, const float* __restrict__ att_dst,
    float* __restrict__ as_, float* __restrict__ ad_) {
    __shared__ float Wt[32][128];
    __shared__ float Xt[64][33];
    int row0 = blockIdx.x * 64;
    int tx = threadIdx.x & 31;
    int ty = threadIdx.x >> 5;
    float acc[8][4] = {};
    for (int kt = 0; kt < 128; kt += 32) {
        for (int i = threadIdx.x; i < 32 * 128; i += 256)
            Wt[i >> 7][i & 127] = W[(kt + (i >> 7)) * 128 + (i & 127)];
        for (int i = threadIdx.x; i < 64 * 32; i += 256) {
            int r = i >> 5, k = i & 31;
            int row = row0 + r;
            float v = (row < nrows) ? X[(size_t)row * 128 + kt + k] : 0.0f;
            if (APPLY_ACT) {
                float sc = bnparam[kt + k], sh = bnparam[128 + kt + k];
                v = sc * v + sh;
                v = v > 0.0f ? v : (expf(v) - 1.0f);
            }
            Xt[r][k] = v;
        }
        __syncthreads();
        for (int k = 0; k < 32; ++k) {
            float wv[4];
#pragma unroll
            for (int j = 0; j < 4; ++j) wv[j] = Wt[k][tx + 32 * j];
#pragma unroll
            for (int i = 0; i < 8; ++i) {
                float xv = Xt[ty + 8 * i][k];
#pragma unroll
                for (int j = 0; j < 4; ++j) acc[i][j] += xv * wv[j];
            }
        }
        __syncthreads();
    }
    // att vectors for this thread's 4 columns (cols tx+32j; head = j>>1)
    float avs0 = att_src[tx],      avs1 = att_src[tx + 32];
    float avs2 = att_src[64 + tx], avs3 = att_src[96 + tx];
    float avd0 = att_dst[tx],      avd1 = att_dst[tx + 32];
    float avd2 = att_dst[64 + tx], avd3 = att_dst[96 + tx];
    for (int i = 0; i < 8; ++i) {
        int row = row0 + ty + 8 * i;
        if (row < nrows) {
#pragma unroll
            for (int j = 0; j < 4; ++j)
                Out[(size_t)row * 128 + tx + 32 * j] = f2bf(acc[i][j]);
        }
        // attention dots: reduce over the 32 tx-lanes sharing this row
        float as0 = acc[i][0] * avs0 + acc[i][1] * avs1;
        float as1 = acc[i][2] * avs2 + acc[i][3] * avs3;
        float ad0 = acc[i][0] * avd0 + acc[i][1] * avd1;
        float ad1 = acc[i][2] * avd2 + acc[i][3] * avd3;
        for (int off = 16; off; off >>= 1) {
            as0 += __shfl_down(as0, off, 32);
            as1 += __shfl_down(as1, off, 32);
            ad0 += __shfl_down(ad0, off, 32);
            ad1 += __shfl_down(ad1, off, 32);
        }
        if (tx == 0 && row < nrows) {
            as_[row * 2] = as0; as_[row * 2 + 1] = as1;
            ad_[row * 2] = ad0; ad_[row * 2 + 1] = ad1;
        }
    }
}

// -------- CSR build ---------------------------------------------------------
__global__ __launch_bounds__(256) void hist_k(const int* __restrict__ dst_arr,
                                              int E_, int* __restrict__ cnt) {
    int tid = blockIdx.x * blockDim.x + threadIdx.x;
    int stride = gridDim.x * blockDim.x;
    for (int e = tid; e < E_; e += stride) atomicAdd(&cnt[dst_arr[e]], 1);
}

__global__ __launch_bounds__(256) void scan_part_k(const int* __restrict__ cnt,
                                                   int Nn, int* __restrict__ partial) {
    int b = blockIdx.x;
    int beg = b * SCHUNK, end = min(Nn, beg + SCHUNK);
    int s = 0;
    for (int i = beg + threadIdx.x; i < end; i += 256) s += cnt[i];
    for (int off = 32; off; off >>= 1) s += __shfl_down(s, off);
    __shared__ int wsum[4];
    int lane = threadIdx.x & 63, w = threadIdx.x >> 6;
    if (lane == 0) wsum[w] = s;
    __syncthreads();
    if (threadIdx.x == 0) partial[b] = wsum[0] + wsum[1] + wsum[2] + wsum[3];
}

__global__ void scan_psum_k(int* __restrict__ partial, int NB,
                            int* __restrict__ rowptr, int Nn) {
    if (threadIdx.x == 0) {
        int run = 0;
        for (int i = 0; i < NB; ++i) { int t = partial[i]; partial[i] = run; run += t; }
        rowptr[Nn] = run;
    }
}

__global__ __launch_bounds__(256) void scan_final_k(int* __restrict__ cntcur, int Nn,
                                                    const int* __restrict__ partial,
                                                    int* __restrict__ rowptr) {
    int b = blockIdx.x;
    int t = threadIdx.x;
    int i0 = b * SCHUNK + t * 16;
    int v[16];
    int s = 0;
#pragma unroll
    for (int k = 0; k < 16; ++k) {
        int i = i0 + k;
        int val = (i < Nn) ? cntcur[i] : 0;
        v[k] = s; s += val;
    }
    int lane = t & 63, w = t >> 6;
    int x = s;
    for (int off = 1; off < 64; off <<= 1) {
        int r = __shfl_up(x, off);
        if (lane >= off) x += r;
    }
    __shared__ int wsum[4], woff[4];
    if (lane == 63) wsum[w] = x;
    __syncthreads();
    if (t == 0) { int run = 0; for (int j = 0; j < 4; ++j) { woff[j] = run; run += wsum[j]; } }
    __syncthreads();
    int excl = x - s + woff[w] + partial[b];
#pragma unroll
    for (int k = 0; k < 16; ++k) {
        int i = i0 + k;
        if (i < Nn) { int e = excl + v[k]; rowptr[i] = e; cntcur[i] = e; }
    }
}

__global__ __launch_bounds__(256) void scatter_k(const int* __restrict__ src_arr,
                                                 const int* __restrict__ dst_arr,
                                                 int E_, int* __restrict__ cursor,
                                                 int* __restrict__ csr) {
    int tid = blockIdx.x * blockDim.x + threadIdx.x;
    int stride = gridDim.x * blockDim.x;
    for (int e = tid; e < E_; e += stride) {
        int d = dst_arr[e];
        int pos = atomicAdd(&cursor[d], 1);
        csr[pos] = src_arr[e];
    }
}

// -------- gather: one wave/node, single pass, online softmax ----------------
// Per 64-edge chunk: lane-parallel logits+exp, shfl max/den reduce (with
// online rescale), stage {p0,s,p1,s} (16B) in wave-private LDS, then a
// serial accumulate reading ds_read_b64 {p_head, s} (2-way broadcast, free)
// with 4 gather loads kept in flight.
// LAYER 1: outp = y[n,128] fp32 = agg + b1 ; BN col sums into bnsum
// LAYER 2: outp = out[n,64] fp32 = 0.5*(head0+head1) + b2
template <int LAYER>
__global__ __launch_bounds__(256) void gather_k(
    const int* __restrict__ csr, const int* __restrict__ rowptr,
    const float* __restrict__ as_, const float* __restrict__ ad_,
    const unsigned short* __restrict__ hfeat, float* __restrict__ outp,
    const float* __restrict__ bias, float* __restrict__ bnsum, int Nn) {
    __shared__ int4 sPS[4][64];            // per-wave staging {p0,s,p1,s}
    int lane = threadIdx.x & 63;
    int wv = threadIdx.x >> 6;
    int wid = (blockIdx.x * blockDim.x + threadIdx.x) >> 6;
    int nw = (gridDim.x * blockDim.x) >> 6;
    const unsigned int* h4 = (const unsigned int*)hfeat;  // 2 bf16 per uint
    const float2* as2 = (const float2*)as_;
    const float2* ad2 = (const float2*)ad_;
    int head = lane >> 5;
    int4* mPS = sPS[wv];
    const int2* mPS2 = (const int2*)mPS;   // index jj*2 + head
    float bnS0 = 0, bnS1 = 0, bnQ0 = 0, bnQ1 = 0;
    for (int n = wid; n < Nn; n += nw) {
        int beg = rowptr[n], deg = rowptr[n + 1] - beg;
        float2 adn = ad2[n];
        float2 asn = as2[n];
        float es0 = asn.x + adn.x; es0 = es0 > 0.f ? es0 : NEG_SLOPE * es0;
        float es1 = asn.y + adn.y; es1 = es1 > 0.f ? es1 : NEG_SLOPE * es1;
        float m0 = es0, m1 = es1;          // running max per head
        float den0 = 1.f, den1 = 1.f;      // self-loop: p = 1
        unsigned int hu = h4[(size_t)n * 64 + lane];
        float accx = bf_lo(hu), accy = bf_hi(hu);
        for (int j0 = 0; j0 < deg; j0 += 64) {
            int cnt = min(64, deg - j0);
            float t0 = -3.4e38f, t1 = -3.4e38f;
            int s = 0;
            if (lane < cnt) {
                s = csr[beg + j0 + lane];
                float2 a = as2[s];
                t0 = a.x + adn.x; t0 = t0 > 0.f ? t0 : NEG_SLOPE * t0;
                t1 = a.y + adn.y; t1 = t1 > 0.f ? t1 : NEG_SLOPE * t1;
            }
            float cm0 = t0, cm1 = t1;
            for (int off = 32; off; off >>= 1) {
                cm0 = fmaxf(cm0, __shfl_xor(cm0, off));
                cm1 = fmaxf(cm1, __shfl_xor(cm1, off));
            }
            if (cm0 > m0 || cm1 > m1) {    // wave-uniform rescale
                float nm0 = fmaxf(m0, cm0), nm1 = fmaxf(m1, cm1);
                float sc0 = expf(m0 - nm0), sc1 = expf(m1 - nm1);
                den0 *= sc0; den1 *= sc1;
                float sch = head ? sc1 : sc0;
                accx *= sch; accy *= sch;
                m0 = nm0; m1 = nm1;
            }
            float p0 = 0.f, p1 = 0.f;
            if (lane < cnt) {
                p0 = expf(t0 - m0);
                p1 = expf(t1 - m1);
                mPS[lane] = make_int4(__float_as_int(p0), s, __float_as_int(p1), s);
            }
            float d0 = p0, d1 = p1;
            for (int off = 32; off; off >>= 1) {
                d0 += __shfl_xor(d0, off);
                d1 += __shfl_xor(d1, off);
            }
            den0 += d0; den1 += d1;
            // serial accumulate (DS ops of a wave execute in program order;
            // wave-private region -> no barrier needed)
#pragma unroll 4
            for (int jj = 0; jj < cnt; ++jj) {
                int2 ps = mPS2[jj * 2 + head];
                float p = __int_as_float(ps.x);
                unsigned off2 = ((unsigned)ps.y << 6) + lane;
                unsigned int hv = h4[off2];
                accx += p * bf_lo(hv);
                accy += p * bf_hi(hv);
            }
        }
        float inv = 1.0f / (head ? den1 : den0);
        if (LAYER == 1) {
            float2 bb = ((const float2*)bias)[lane];
            float2 v; v.x = accx * inv + bb.x; v.y = accy * inv + bb.y;
            ((float2*)outp)[(size_t)n * 64 + lane] = v;
            bnS0 += v.x; bnS1 += v.y; bnQ0 += v.x * v.x; bnQ1 += v.y * v.y;
        } else {
            float vx = accx * inv, vy = accy * inv;
            float vx2 = __shfl(vx, lane + 32);
            float vy2 = __shfl(vy, lane + 32);
            if (lane < 32) {
                float2 bb = ((const float2*)bias)[lane];
                float2 o;
                o.x = 0.5f * (vx + vx2) + bb.x;
                o.y = 0.5f * (vy + vy2) + bb.y;
                ((float2*)outp)[(size_t)n * 32 + lane] = o;
            }
        }
    }
    if (LAYER == 1) {
        __shared__ float lsum[128], lsq[128];
        if (threadIdx.x < 128) { lsum[threadIdx.x] = 0.f; lsq[threadIdx.x] = 0.f; }
        __syncthreads();
        atomicAdd(&lsum[2 * lane], bnS0);
        atomicAdd(&lsum[2 * lane + 1], bnS1);
        atomicAdd(&lsq[2 * lane], bnQ0);
        atomicAdd(&lsq[2 * lane + 1], bnQ1);
        __syncthreads();
        if (threadIdx.x < 128) {
            atomicAdd(&bnsum[threadIdx.x], lsum[threadIdx.x]);
            atomicAdd(&bnsum[128 + threadIdx.x], lsq[threadIdx.x]);
        }
    }
}

// -------- BN param finalize -------------------------------------------------
__global__ void bn_final_k(const float* __restrict__ bnsum,
                           const float* __restrict__ gamma,
                           const float* __restrict__ beta,
                           float* __restrict__ bnparam, float invN) {
    int c = threadIdx.x;
    if (c < 128) {
        float mu = bnsum[c] * invN;
        float var = bnsum[128 + c] * invN - mu * mu;
        float sc = gamma[c] * rsqrtf(var + BN_EPS);
        bnparam[c] = sc;
        bnparam[128 + c] = beta[c] - mu * sc;
    }
}

extern "C" void kernel_launch(void* const* d_in, const int* in_sizes, int n_in,
                              void* d_out, int out_size, void* d_ws, size_t ws_size,
                              hipStream_t stream) {
    const float* x        = (const float*)d_in[0];
    const int*   ei       = (const int*)d_in[1];
    const float* W1       = (const float*)d_in[2];
    const float* att_src1 = (const float*)d_in[3];
    const float* att_dst1 = (const float*)d_in[4];
    const float* b1       = (const float*)d_in[5];
    const float* gamma1   = (const float*)d_in[6];
    const float* beta1    = (const float*)d_in[7];
    const float* W2       = (const float*)d_in[8];
    const float* att_src2 = (const float*)d_in[9];
    const float* att_dst2 = (const float*)d_in[10];
    const float* b2       = (const float*)d_in[11];
    float* out = (float*)d_out;

    const int Nn = in_sizes[0] / 128;
    const int E_ = in_sizes[1] / 2;
    const int* src_arr = ei;
    const int* dst_arr = ei + E_;

    float* ws = (float*)d_ws;
    auto a4 = [](size_t v) { return (v + 3) & ~(size_t)3; };
    size_t off = 0;
    size_t offCnt   = off; off = a4(off + (size_t)Nn);          // cnt/cursor (int)
    size_t offBnsum = off; off = a4(off + 256);                 // zeroed with cnt
    size_t zeroCnt  = off;                                      // [0,zeroCnt) zeroed
    size_t offRow   = off; off = a4(off + (size_t)Nn + 1);      // rowptr (int)
    size_t offPart  = off; off = a4(off + 256);                 // scan partials (int)
    size_t offAs    = off; off = a4(off + (size_t)Nn * 2);
    size_t offAd    = off; off = a4(off + (size_t)Nn * 2);
    size_t offBnp   = off; off = a4(off + 256);
    size_t offCsr   = off; off = a4(off + (size_t)E_);          // csr src (int)
    size_t offY     = off; off = a4(off + (size_t)Nn * 128);    // y fp32
    size_t offH1    = off; off = a4(off + (size_t)Nn * 64);     // h1 bf16 (ushort)
    size_t offH2    = off; off = a4(off + (size_t)Nn * 64);     // h2 bf16 (ushort)

    int*   cnt     = (int*)(ws + offCnt);
    float* bnsum   = ws + offBnsum;
    int*   rowptr  = (int*)(ws + offRow);
    int*   partial = (int*)(ws + offPart);
    float* as_     = ws + offAs;
    float* ad_     = ws + offAd;
    float* bnparam = ws + offBnp;
    int*   csr     = (int*)(ws + offCsr);
    float* Y       = ws + offY;
    unsigned short* H1 = (unsigned short*)(ws + offH1);
    unsigned short* H2 = (unsigned short*)(ws + offH2);

    hipMemsetAsync(ws, 0, zeroCnt * sizeof(float), stream);

    // CSR build
    int NB = (Nn + SCHUNK - 1) / SCHUNK;
    hist_k<<<2048, 256, 0, stream>>>(dst_arr, E_, cnt);
    scan_part_k<<<NB, 256, 0, stream>>>(cnt, Nn, partial);
    scan_psum_k<<<1, 64, 0, stream>>>(partial, NB, rowptr, Nn);
    scan_final_k<<<NB, 256, 0, stream>>>(cnt, Nn, partial, rowptr);
    scatter_k<<<2048, 256, 0, stream>>>(src_arr, dst_arr, E_, cnt, csr);

    int gemmBlocks = (Nn + 63) / 64;
    // layer 1
    gemm128_k<0><<<gemmBlocks, 256, 0, stream>>>(x, W1, H1, Nn, nullptr,
                                                 att_src1, att_dst1, as_, ad_);
    gather_k<1><<<2048, 256, 0, stream>>>(csr, rowptr, as_, ad_, H1, Y, b1, bnsum, Nn);
    bn_final_k<<<1, 128, 0, stream>>>(bnsum, gamma1, beta1, bnparam, 1.0f / (float)Nn);
    // layer 2
    gemm128_k<1><<<gemmBlocks, 256, 0, stream>>>(Y, W2, H2, Nn, bnparam,
                                                 att_src2, att_dst2, as_, ad_);
    gather_k<2><<<2048, 256, 0, stream>>>(csr, rowptr, as_, ad_, H2, out, b2, nullptr, Nn);

    (void)n_in; (void)out_size; (void)ws_size;
}